// Round 1
// baseline (1504.424 us; speedup 1.0000x reference)
//
#include <hip/hip_runtime.h>
#include <hip/hip_bf16.h>
#include <stdint.h>

// ChainOfExperts MoE: shared 2-expert MLP + top-2-of-16 routed experts.
// T=16384 tokens, D=2048, DR=512, DS=1024. bf16 MFMA compute, f32 router.

#define DEV static __device__ __forceinline__

typedef __attribute__((ext_vector_type(8))) short bf16x8;
typedef __attribute__((ext_vector_type(4))) float f32x4;

constexpr int T_TOK = 16384;
constexpr int DIM   = 2048;
constexpr int NEXP  = 16;
constexpr int DR_K  = 512;
constexpr int DS_K  = 1024;
constexpr int MAXROWS = 34816;  // T*K + E*127 rounded up

DEV void gload16(const void* g, void* l) {
  __builtin_amdgcn_global_load_lds(
      (const __attribute__((address_space(1))) unsigned int*)g,
      (__attribute__((address_space(3))) unsigned int*)l, 16, 0, 0);
}

DEV float silu_f(float v) { return v / (1.f + __expf(-v)); }

// ---------------- cast x f32 -> bf16 ----------------
__global__ void cast_kernel(const float* __restrict__ in, __hip_bfloat16* __restrict__ out) {
  size_t i = (size_t)blockIdx.x * blockDim.x + threadIdx.x;  // 8 elems per thread
  const float4* p = (const float4*)in;
  float4 v0 = p[2 * i], v1 = p[2 * i + 1];
  union { bf16x8 v; __hip_bfloat16 h[8]; } r;
  r.h[0] = __float2bfloat16(v0.x); r.h[1] = __float2bfloat16(v0.y);
  r.h[2] = __float2bfloat16(v0.z); r.h[3] = __float2bfloat16(v0.w);
  r.h[4] = __float2bfloat16(v1.x); r.h[5] = __float2bfloat16(v1.y);
  r.h[6] = __float2bfloat16(v1.z); r.h[7] = __float2bfloat16(v1.w);
  ((bf16x8*)out)[i] = r.v;
}

// ---------------- transpose + cast: in[R][C] f32 -> out[C][R] bf16, batched z ----------------
__global__ void transpose_cast(const float* __restrict__ in, __hip_bfloat16* __restrict__ out,
                               int R, int C) {
  __shared__ float t[32][33];
  size_t bo = (size_t)blockIdx.z * R * C;
  in += bo; out += bo;
  int c0 = blockIdx.x * 32, r0 = blockIdx.y * 32;
  int tx = threadIdx.x & 31, ty = threadIdx.x >> 5;  // 32x8
#pragma unroll
  for (int i = 0; i < 32; i += 8)
    t[ty + i][tx] = in[(size_t)(r0 + ty + i) * C + c0 + tx];
  __syncthreads();
#pragma unroll
  for (int i = 0; i < 32; i += 8)
    out[(size_t)(c0 + ty + i) * R + r0 + tx] = __float2bfloat16(t[tx][ty + i]);
}

// ---------------- router: f32 logits, softmax, top-2 ----------------
__global__ void router_kernel(const float* __restrict__ x, const float* __restrict__ rw_all,
                              const int* __restrict__ step_p, int* __restrict__ tk_idx,
                              float* __restrict__ tk_w, int* __restrict__ cnt) {
  int t = blockIdx.x, tid = threadIdx.x;
  const float* rw = rw_all + (size_t)step_p[0] * DIM * NEXP;  // [D][16]
  const float* xr = x + (size_t)t * DIM;
  int e = tid & 15, ch = tid >> 4;  // 16 experts x 16 chunks of 128
  float p = 0.f;
  int d0 = ch * (DIM / 16);
  for (int d = 0; d < DIM / 16; ++d)
    p += xr[d0 + d] * rw[(size_t)(d0 + d) * NEXP + e];
  __shared__ float part[16][17];
  __shared__ float logit[16];
  part[ch][e] = p;
  __syncthreads();
  if (tid < 16) {
    float s = 0.f;
    for (int c = 0; c < 16; ++c) s += part[c][tid];
    logit[tid] = s;
  }
  __syncthreads();
  if (tid == 0) {
    float mx = logit[0];
    for (int i = 1; i < 16; ++i) mx = fmaxf(mx, logit[i]);
    float pr[16], sum = 0.f;
    for (int i = 0; i < 16; ++i) { pr[i] = expf(logit[i] - mx); sum += pr[i]; }
    float inv = 1.f / sum;
    int b0 = -1, b1 = -1; float v0 = -1.f, v1 = -1.f;
    for (int i = 0; i < 16; ++i) {
      float v = pr[i] * inv;
      if (v > v0)      { v1 = v0; b1 = b0; v0 = v; b0 = i; }
      else if (v > v1) { v1 = v; b1 = i; }
    }
    tk_idx[2 * t] = b0; tk_idx[2 * t + 1] = b1;
    tk_w[2 * t] = v0;   tk_w[2 * t + 1] = v1;
    atomicAdd(&cnt[b0], 1); atomicAdd(&cnt[b1], 1);
  }
}

// ---------------- scan: padded counts + exclusive offsets ----------------
__global__ void scan_kernel(const int* __restrict__ cnt, int* __restrict__ seg,
                            int* __restrict__ padded) {
  if (threadIdx.x == 0) {
    int off = 0;
    for (int e = 0; e < NEXP; ++e) {
      seg[e] = off;
      int pc = (cnt[e] + 127) & ~127;
      padded[e] = pc;
      off += pc;
    }
    seg[NEXP] = off;
  }
}

// ---------------- scatter tokens into per-expert lists ----------------
__global__ void scatter_kernel(const int* __restrict__ tk_idx, const float* __restrict__ tk_w,
                               const int* __restrict__ seg, int* __restrict__ cnt2,
                               int* __restrict__ tok_list, float* __restrict__ w_list) {
  int t = blockIdx.x * 256 + threadIdx.x;
  if (t >= T_TOK) return;
#pragma unroll
  for (int k = 0; k < 2; ++k) {
    int e = tk_idx[2 * t + k];
    int slot = atomicAdd(&cnt2[e], 1);
    int pos = seg[e] + slot;
    tok_list[pos] = t;
    w_list[pos] = tk_w[2 * t + k];
  }
}

// ---------------- pad lists to multiple of 128 (tok 0, weight 0) ----------------
__global__ void pad_kernel(const int* __restrict__ cnt, const int* __restrict__ padded,
                           const int* __restrict__ seg, int* __restrict__ tok_list,
                           float* __restrict__ w_list) {
  int e = blockIdx.x;
  int c = cnt[e], pc = padded[e], s = seg[e];
  for (int i = c + threadIdx.x; i < pc; i += blockDim.x) {
    tok_list[s + i] = 0;
    w_list[s + i] = 0.f;
  }
}

// ---------------- 128x128 MFMA GEMM, m97 structure ----------------
// MODE 0: shared L1  (A=xb, Bt=w1t_sh concat-N 2048, silu -> h_sh bf16)
// MODE 1: shared L2  (A=h_sh, Bt=w2t_sh, +sum(sh_b2) -> out f32 store)
// MODE 2: routed L1  (A=xb gathered by token list, Bt=w1t_re[e], silu*cw -> h_re bf16)
// MODE 3: routed L2  (A=h_re, Bt=w2t_re[e], atomicAdd into out f32)
template <int MODE>
__global__ __launch_bounds__(256)
void gemm_kernel(const __hip_bfloat16* __restrict__ Abase,
                 const __hip_bfloat16* __restrict__ Bt,
                 const float* __restrict__ bias,
                 __hip_bfloat16* __restrict__ outb,
                 float* __restrict__ outf,
                 const int* __restrict__ tok_list,
                 const float* __restrict__ w_list,
                 const int* __restrict__ seg_off,
                 const int* __restrict__ padded_cnt) {
  constexpr int KD = (MODE == 3) ? DR_K : DIM;  // lda == K for all operands
  int tid = threadIdx.x;
  int lane = tid & 63, wid = tid >> 6;
  int wr = wid >> 1, wc = wid & 1;
  int n0 = blockIdx.x * 128;
  int m0 = blockIdx.y * 128;
  int e = blockIdx.z;

  __shared__ __hip_bfloat16 Alds[128 * 32];
  __shared__ __hip_bfloat16 Blds[128 * 32];
  __shared__ int tk_s[128];
  __shared__ float w_s[128];

  int seg = 0;
  if constexpr (MODE >= 2) {
    seg = seg_off[e];
    if (m0 >= padded_cnt[e]) return;
    if (tid < 128) {
      tk_s[tid] = tok_list[seg + m0 + tid];
      w_s[tid] = w_list[seg + m0 + tid];
    }
    __syncthreads();
  }

  // staging geometry: idx = issue*256 + tid; row = idx>>2 (0..127); 16B chunk = idx&3
  int srow = tid >> 2;
  int kcol = (tid & 3) << 3;  // element offset within row
  const __hip_bfloat16 *Ag0, *Ag1, *Bg0, *Bg1;
  if constexpr (MODE == 0 || MODE == 1) {
    Ag0 = Abase + (size_t)(m0 + srow) * KD + kcol;
    Ag1 = Abase + (size_t)(m0 + srow + 64) * KD + kcol;
  } else if constexpr (MODE == 2) {
    Ag0 = Abase + (size_t)tk_s[srow] * KD + kcol;
    Ag1 = Abase + (size_t)tk_s[srow + 64] * KD + kcol;
  } else {
    Ag0 = Abase + (size_t)(seg + m0 + srow) * KD + kcol;
    Ag1 = Abase + (size_t)(seg + m0 + srow + 64) * KD + kcol;
  }
  if constexpr (MODE == 0) {
    int s = n0 >> 10, nn = n0 & 1023;
    Bg0 = Bt + ((size_t)s * DS_K + nn + srow) * KD + kcol;
    Bg1 = Bt + ((size_t)s * DS_K + nn + srow + 64) * KD + kcol;
  } else if constexpr (MODE == 1) {
    Bg0 = Bt + (size_t)(n0 + srow) * KD + kcol;
    Bg1 = Bt + (size_t)(n0 + srow + 64) * KD + kcol;
  } else if constexpr (MODE == 2) {
    Bg0 = Bt + ((size_t)e * DR_K + n0 + srow) * KD + kcol;
    Bg1 = Bt + ((size_t)e * DR_K + n0 + srow + 64) * KD + kcol;
  } else {
    Bg0 = Bt + ((size_t)e * DIM + n0 + srow) * KD + kcol;
    Bg1 = Bt + ((size_t)e * DIM + n0 + srow + 64) * KD + kcol;
  }

  char* AldsW0 = (char*)Alds + wid * 1024;
  char* AldsW1 = (char*)Alds + 4096 + wid * 1024;
  char* BldsW0 = (char*)Blds + wid * 1024;
  char* BldsW1 = (char*)Blds + 4096 + wid * 1024;

  f32x4 acc[4][4];
#pragma unroll
  for (int i = 0; i < 4; ++i)
#pragma unroll
    for (int j = 0; j < 4; ++j) acc[i][j] = (f32x4){0.f, 0.f, 0.f, 0.f};

  int arow_rd = wr * 64 + (lane & 15);
  int brow_rd = wc * 64 + (lane & 15);
  int krd = (lane >> 4) << 3;

  for (int k0 = 0; k0 < KD; k0 += 32) {
    gload16(Ag0 + k0, AldsW0);
    gload16(Ag1 + k0, AldsW1);
    gload16(Bg0 + k0, BldsW0);
    gload16(Bg1 + k0, BldsW1);
    __syncthreads();  // drains vmcnt before barrier
    bf16x8 a[4], b[4];
    const short* As = (const short*)Alds;
    const short* Bs = (const short*)Blds;
#pragma unroll
    for (int i = 0; i < 4; ++i) {
      a[i] = *(const bf16x8*)(As + (arow_rd + i * 16) * 32 + krd);
      b[i] = *(const bf16x8*)(Bs + (brow_rd + i * 16) * 32 + krd);
    }
#pragma unroll
    for (int mi = 0; mi < 4; ++mi)
#pragma unroll
      for (int ni = 0; ni < 4; ++ni)
        acc[mi][ni] = __builtin_amdgcn_mfma_f32_16x16x32_bf16(a[mi], b[ni], acc[mi][ni], 0, 0, 0);
    __syncthreads();
  }

  // epilogue: C row (reg dim) = A row, C col (lane&15) = Bt row
  int colc = lane & 15;
  int rowb = (lane >> 4) << 2;
#pragma unroll
  for (int mi = 0; mi < 4; ++mi) {
    int mloc = wr * 64 + mi * 16 + rowb;
#pragma unroll
    for (int ni = 0; ni < 4; ++ni) {
      int ng = n0 + wc * 64 + ni * 16 + colc;
#pragma unroll
      for (int j = 0; j < 4; ++j) {
        float v = acc[mi][ni][j];
        int ml = mloc + j;
        if constexpr (MODE == 0) {
          float s = silu_f(v + bias[ng]);  // sh_b1 flat [2*DS] == concat index
          outb[(size_t)(m0 + ml) * 2048 + ng] = __float2bfloat16(s);
        } else if constexpr (MODE == 1) {
          outf[(size_t)(m0 + ml) * DIM + ng] = v + bias[ng] + bias[DIM + ng];
        } else if constexpr (MODE == 2) {
          float s = silu_f(v + bias[(size_t)e * DR_K + ng]) * w_s[ml];
          outb[((size_t)seg + m0 + ml) * DR_K + ng] = __float2bfloat16(s);
        } else {
          float wv = w_s[ml];
          atomicAdd(&outf[(size_t)tk_s[ml] * DIM + ng],
                    v + wv * bias[(size_t)e * DIM + ng]);
        }
      }
    }
  }
}

extern "C" void kernel_launch(void* const* d_in, const int* in_sizes, int n_in,
                              void* d_out, int out_size, void* d_ws, size_t ws_size,
                              hipStream_t stream) {
  const float* x     = (const float*)d_in[0];
  const int* step_p  = (const int*)d_in[1];
  const float* rw    = (const float*)d_in[2];
  const float* re_w1 = (const float*)d_in[3];
  const float* re_b1 = (const float*)d_in[4];
  const float* re_w2 = (const float*)d_in[5];
  const float* re_b2 = (const float*)d_in[6];
  const float* sh_w1 = (const float*)d_in[7];
  const float* sh_b1 = (const float*)d_in[8];
  const float* sh_w2 = (const float*)d_in[9];
  const float* sh_b2 = (const float*)d_in[10];
  float* out = (float*)d_out;

  char* w = (char*)d_ws;
  auto take = [&](size_t bytes) {
    char* p = w;
    w += (bytes + 255) & ~(size_t)255;
    return p;
  };
  __hip_bfloat16* xb     = (__hip_bfloat16*)take((size_t)T_TOK * DIM * 2);
  __hip_bfloat16* h_sh   = (__hip_bfloat16*)take((size_t)T_TOK * 2048 * 2);
  __hip_bfloat16* h_re   = (__hip_bfloat16*)take((size_t)MAXROWS * DR_K * 2);
  __hip_bfloat16* w1t_sh = (__hip_bfloat16*)take((size_t)2 * DS_K * DIM * 2);
  __hip_bfloat16* w2t_sh = (__hip_bfloat16*)take((size_t)DIM * 2048 * 2);
  __hip_bfloat16* w1t_re = (__hip_bfloat16*)take((size_t)NEXP * DR_K * DIM * 2);
  __hip_bfloat16* w2t_re = (__hip_bfloat16*)take((size_t)NEXP * DIM * DR_K * 2);
  int* tk_idx   = (int*)take((size_t)T_TOK * 2 * 4);
  float* tk_w   = (float*)take((size_t)T_TOK * 2 * 4);
  int* ctrl     = (int*)take(512);
  int* tok_list = (int*)take((size_t)MAXROWS * 4);
  float* w_list = (float*)take((size_t)MAXROWS * 4);
  int* cnt = ctrl, *cnt2 = ctrl + 16, *seg = ctrl + 32, *padded = ctrl + 56;

  hipMemsetAsync(ctrl, 0, 512, stream);
  cast_kernel<<<T_TOK * DIM / 8 / 256, 256, 0, stream>>>(x, xb);
  transpose_cast<<<dim3(DS_K / 32, DIM / 32, 2), 256, 0, stream>>>(sh_w1, w1t_sh, DIM, DS_K);
  transpose_cast<<<dim3(DIM / 32, 2048 / 32, 1), 256, 0, stream>>>(sh_w2, w2t_sh, 2048, DIM);
  transpose_cast<<<dim3(DR_K / 32, DIM / 32, NEXP), 256, 0, stream>>>(re_w1, w1t_re, DIM, DR_K);
  transpose_cast<<<dim3(DIM / 32, DR_K / 32, NEXP), 256, 0, stream>>>(re_w2, w2t_re, DR_K, DIM);
  router_kernel<<<T_TOK, 256, 0, stream>>>(x, rw, step_p, tk_idx, tk_w, cnt);
  scan_kernel<<<1, 32, 0, stream>>>(cnt, seg, padded);
  scatter_kernel<<<T_TOK / 256, 256, 0, stream>>>(tk_idx, tk_w, seg, cnt2, tok_list, w_list);
  pad_kernel<<<NEXP, 128, 0, stream>>>(cnt, padded, seg, tok_list, w_list);

  // shared L1: [T,2048] = xb @ concat(sh_w1), silu -> h_sh
  gemm_kernel<0><<<dim3(16, 128, 1), 256, 0, stream>>>(xb, w1t_sh, sh_b1, h_sh, nullptr,
                                                       nullptr, nullptr, nullptr, nullptr);
  // routed L1: gathered rows -> h_re (cw folded in)
  gemm_kernel<2><<<dim3(4, 128, NEXP), 256, 0, stream>>>(xb, w1t_re, re_b1, h_re, nullptr,
                                                         tok_list, w_list, seg, padded);
  // shared L2: writes out (f32 store, covers all of out)
  gemm_kernel<1><<<dim3(16, 128, 1), 256, 0, stream>>>(h_sh, w2t_sh, sh_b2, nullptr, out,
                                                       nullptr, nullptr, nullptr, nullptr);
  // routed L2: atomicAdd scatter into out
  gemm_kernel<3><<<dim3(16, 128, NEXP), 256, 0, stream>>>(h_re, w2t_re, re_b2, nullptr, out,
                                                          tok_list, w_list, seg, padded);
}

// Round 2
// 1280.965 us; speedup vs baseline: 1.1744x; 1.1744x over previous
//
#include <hip/hip_runtime.h>
#include <hip/hip_bf16.h>
#include <stdint.h>

// ChainOfExperts MoE: shared 2-expert MLP + top-2-of-16 routed experts.
// T=16384 tokens, D=2048, DR=512, DS=1024. bf16 MFMA compute, f32 router.
// R2: routed-L2 atomic scatter replaced by dense y_re buffer + gather-combine.

#define DEV static __device__ __forceinline__

typedef __attribute__((ext_vector_type(8))) short bf16x8;
typedef __attribute__((ext_vector_type(4))) float f32x4;

constexpr int T_TOK = 16384;
constexpr int DIM   = 2048;
constexpr int NEXP  = 16;
constexpr int DR_K  = 512;
constexpr int DS_K  = 1024;
constexpr int MAXROWS = 34816;  // T*K + E*127 rounded up

DEV void gload16(const void* g, void* l) {
  __builtin_amdgcn_global_load_lds(
      (const __attribute__((address_space(1))) unsigned int*)g,
      (__attribute__((address_space(3))) unsigned int*)l, 16, 0, 0);
}

DEV float silu_f(float v) { return v / (1.f + __expf(-v)); }

// ---------------- cast x f32 -> bf16 ----------------
__global__ void cast_kernel(const float* __restrict__ in, __hip_bfloat16* __restrict__ out) {
  size_t i = (size_t)blockIdx.x * blockDim.x + threadIdx.x;  // 8 elems per thread
  const float4* p = (const float4*)in;
  float4 v0 = p[2 * i], v1 = p[2 * i + 1];
  union { bf16x8 v; __hip_bfloat16 h[8]; } r;
  r.h[0] = __float2bfloat16(v0.x); r.h[1] = __float2bfloat16(v0.y);
  r.h[2] = __float2bfloat16(v0.z); r.h[3] = __float2bfloat16(v0.w);
  r.h[4] = __float2bfloat16(v1.x); r.h[5] = __float2bfloat16(v1.y);
  r.h[6] = __float2bfloat16(v1.z); r.h[7] = __float2bfloat16(v1.w);
  ((bf16x8*)out)[i] = r.v;
}

// ---------------- transpose + cast: in[R][C] f32 -> out[C][R] bf16, batched z ----------------
__global__ void transpose_cast(const float* __restrict__ in, __hip_bfloat16* __restrict__ out,
                               int R, int C) {
  __shared__ float t[32][33];
  size_t bo = (size_t)blockIdx.z * R * C;
  in += bo; out += bo;
  int c0 = blockIdx.x * 32, r0 = blockIdx.y * 32;
  int tx = threadIdx.x & 31, ty = threadIdx.x >> 5;  // 32x8
#pragma unroll
  for (int i = 0; i < 32; i += 8)
    t[ty + i][tx] = in[(size_t)(r0 + ty + i) * C + c0 + tx];
  __syncthreads();
#pragma unroll
  for (int i = 0; i < 32; i += 8)
    out[(size_t)(c0 + ty + i) * R + r0 + tx] = __float2bfloat16(t[tx][ty + i]);
}

// ---------------- router: f32 logits, softmax, top-2 ----------------
__global__ void router_kernel(const float* __restrict__ x, const float* __restrict__ rw_all,
                              const int* __restrict__ step_p, int* __restrict__ tk_idx,
                              float* __restrict__ tk_w, int* __restrict__ cnt) {
  int t = blockIdx.x, tid = threadIdx.x;
  const float* rw = rw_all + (size_t)step_p[0] * DIM * NEXP;  // [D][16]
  const float* xr = x + (size_t)t * DIM;
  int e = tid & 15, ch = tid >> 4;  // 16 experts x 16 chunks of 128
  float p = 0.f;
  int d0 = ch * (DIM / 16);
  for (int d = 0; d < DIM / 16; ++d)
    p += xr[d0 + d] * rw[(size_t)(d0 + d) * NEXP + e];
  __shared__ float part[16][17];
  __shared__ float logit[16];
  part[ch][e] = p;
  __syncthreads();
  if (tid < 16) {
    float s = 0.f;
    for (int c = 0; c < 16; ++c) s += part[c][tid];
    logit[tid] = s;
  }
  __syncthreads();
  if (tid == 0) {
    float mx = logit[0];
    for (int i = 1; i < 16; ++i) mx = fmaxf(mx, logit[i]);
    float pr[16], sum = 0.f;
    for (int i = 0; i < 16; ++i) { pr[i] = expf(logit[i] - mx); sum += pr[i]; }
    float inv = 1.f / sum;
    int b0 = -1, b1 = -1; float v0 = -1.f, v1 = -1.f;
    for (int i = 0; i < 16; ++i) {
      float v = pr[i] * inv;
      if (v > v0)      { v1 = v0; b1 = b0; v0 = v; b0 = i; }
      else if (v > v1) { v1 = v; b1 = i; }
    }
    tk_idx[2 * t] = b0; tk_idx[2 * t + 1] = b1;
    tk_w[2 * t] = v0;   tk_w[2 * t + 1] = v1;
    atomicAdd(&cnt[b0], 1); atomicAdd(&cnt[b1], 1);
  }
}

// ---------------- scan: padded counts + exclusive offsets ----------------
__global__ void scan_kernel(const int* __restrict__ cnt, int* __restrict__ seg,
                            int* __restrict__ padded) {
  if (threadIdx.x == 0) {
    int off = 0;
    for (int e = 0; e < NEXP; ++e) {
      seg[e] = off;
      int pc = (cnt[e] + 127) & ~127;
      padded[e] = pc;
      off += pc;
    }
    seg[NEXP] = off;
  }
}

// ---------------- scatter tokens into per-expert lists (+ inverse pos map) ----------------
__global__ void scatter_kernel(const int* __restrict__ tk_idx, const float* __restrict__ tk_w,
                               const int* __restrict__ seg, int* __restrict__ cnt2,
                               int* __restrict__ tok_list, float* __restrict__ w_list,
                               int* __restrict__ pos_list) {
  int t = blockIdx.x * 256 + threadIdx.x;
  if (t >= T_TOK) return;
#pragma unroll
  for (int k = 0; k < 2; ++k) {
    int e = tk_idx[2 * t + k];
    int slot = atomicAdd(&cnt2[e], 1);
    int pos = seg[e] + slot;
    tok_list[pos] = t;
    w_list[pos] = tk_w[2 * t + k];
    pos_list[2 * t + k] = pos;
  }
}

// ---------------- pad lists to multiple of 128 (tok 0, weight 0) ----------------
__global__ void pad_kernel(const int* __restrict__ cnt, const int* __restrict__ padded,
                           const int* __restrict__ seg, int* __restrict__ tok_list,
                           float* __restrict__ w_list) {
  int e = blockIdx.x;
  int c = cnt[e], pc = padded[e], s = seg[e];
  for (int i = c + threadIdx.x; i < pc; i += blockDim.x) {
    tok_list[s + i] = 0;
    w_list[s + i] = 0.f;
  }
}

// ---------------- 128x128 MFMA GEMM body, m97 structure ----------------
// MODE 0: shared L1  (A=xb, Bt=w1t_sh concat-N 2048, silu -> h_sh bf16)
// MODE 1: shared L2  (A=h_sh, Bt=w2t_sh, +sum(sh_b2) -> out f32 store)
// MODE 2: routed L1  (A=xb gathered by token list, Bt=w1t_re[e], silu*cw -> h_re bf16)
// MODE 3: routed L2  (A=h_re, Bt=w2t_re[e], y_re bf16 store, w*bias folded)
template <int MODE>
DEV void gemm_body(const __hip_bfloat16* __restrict__ Abase,
                   const __hip_bfloat16* __restrict__ Bt,
                   const float* __restrict__ bias,
                   __hip_bfloat16* __restrict__ outb,
                   float* __restrict__ outf,
                   const int* __restrict__ tok_list,
                   const float* __restrict__ w_list,
                   const int* __restrict__ seg_off,
                   const int* __restrict__ padded_cnt) {
  constexpr int KD = (MODE == 3) ? DR_K : DIM;  // lda == K for all operands
  int tid = threadIdx.x;
  int lane = tid & 63, wid = tid >> 6;
  int wr = wid >> 1, wc = wid & 1;
  int n0 = blockIdx.x * 128;
  int m0 = blockIdx.y * 128;
  int e = blockIdx.z;

  __shared__ __hip_bfloat16 Alds[128 * 32];
  __shared__ __hip_bfloat16 Blds[128 * 32];
  __shared__ int tk_s[128];
  __shared__ float w_s[128];

  int seg = 0;
  if constexpr (MODE >= 2) {
    seg = seg_off[e];
    if (m0 >= padded_cnt[e]) return;
    if (tid < 128) {
      if constexpr (MODE == 2) tk_s[tid] = tok_list[seg + m0 + tid];
      w_s[tid] = w_list[seg + m0 + tid];
    }
    __syncthreads();
  }

  // staging geometry: row = tid>>2 (0..63), 16B chunk = tid&3
  int srow = tid >> 2;
  int kcol = (tid & 3) << 3;  // element offset within row
  const __hip_bfloat16 *Ag0, *Ag1, *Bg0, *Bg1;
  if constexpr (MODE == 0 || MODE == 1) {
    Ag0 = Abase + (size_t)(m0 + srow) * KD + kcol;
    Ag1 = Abase + (size_t)(m0 + srow + 64) * KD + kcol;
  } else if constexpr (MODE == 2) {
    Ag0 = Abase + (size_t)tk_s[srow] * KD + kcol;
    Ag1 = Abase + (size_t)tk_s[srow + 64] * KD + kcol;
  } else {
    Ag0 = Abase + (size_t)(seg + m0 + srow) * KD + kcol;
    Ag1 = Abase + (size_t)(seg + m0 + srow + 64) * KD + kcol;
  }
  if constexpr (MODE == 0) {
    int s = n0 >> 10, nn = n0 & 1023;
    Bg0 = Bt + ((size_t)s * DS_K + nn + srow) * KD + kcol;
    Bg1 = Bt + ((size_t)s * DS_K + nn + srow + 64) * KD + kcol;
  } else if constexpr (MODE == 1) {
    Bg0 = Bt + (size_t)(n0 + srow) * KD + kcol;
    Bg1 = Bt + (size_t)(n0 + srow + 64) * KD + kcol;
  } else if constexpr (MODE == 2) {
    Bg0 = Bt + ((size_t)e * DR_K + n0 + srow) * KD + kcol;
    Bg1 = Bt + ((size_t)e * DR_K + n0 + srow + 64) * KD + kcol;
  } else {
    Bg0 = Bt + ((size_t)e * DIM + n0 + srow) * KD + kcol;
    Bg1 = Bt + ((size_t)e * DIM + n0 + srow + 64) * KD + kcol;
  }

  char* AldsW0 = (char*)Alds + wid * 1024;
  char* AldsW1 = (char*)Alds + 4096 + wid * 1024;
  char* BldsW0 = (char*)Blds + wid * 1024;
  char* BldsW1 = (char*)Blds + 4096 + wid * 1024;

  f32x4 acc[4][4];
#pragma unroll
  for (int i = 0; i < 4; ++i)
#pragma unroll
    for (int j = 0; j < 4; ++j) acc[i][j] = (f32x4){0.f, 0.f, 0.f, 0.f};

  int arow_rd = wr * 64 + (lane & 15);
  int brow_rd = wc * 64 + (lane & 15);
  int krd = (lane >> 4) << 3;

  for (int k0 = 0; k0 < KD; k0 += 32) {
    gload16(Ag0 + k0, AldsW0);
    gload16(Ag1 + k0, AldsW1);
    gload16(Bg0 + k0, BldsW0);
    gload16(Bg1 + k0, BldsW1);
    __syncthreads();  // drains vmcnt before barrier
    bf16x8 a[4], b[4];
    const short* As = (const short*)Alds;
    const short* Bs = (const short*)Blds;
#pragma unroll
    for (int i = 0; i < 4; ++i) {
      a[i] = *(const bf16x8*)(As + (arow_rd + i * 16) * 32 + krd);
      b[i] = *(const bf16x8*)(Bs + (brow_rd + i * 16) * 32 + krd);
    }
#pragma unroll
    for (int mi = 0; mi < 4; ++mi)
#pragma unroll
      for (int ni = 0; ni < 4; ++ni)
        acc[mi][ni] = __builtin_amdgcn_mfma_f32_16x16x32_bf16(a[mi], b[ni], acc[mi][ni], 0, 0, 0);
    __syncthreads();
  }

  // epilogue: C row (reg dim) = A row, C col (lane&15) = Bt row
  int colc = lane & 15;
  int rowb = (lane >> 4) << 2;
#pragma unroll
  for (int mi = 0; mi < 4; ++mi) {
    int mloc = wr * 64 + mi * 16 + rowb;
#pragma unroll
    for (int ni = 0; ni < 4; ++ni) {
      int ng = n0 + wc * 64 + ni * 16 + colc;
#pragma unroll
      for (int j = 0; j < 4; ++j) {
        float v = acc[mi][ni][j];
        int ml = mloc + j;
        if constexpr (MODE == 0) {
          float s = silu_f(v + bias[ng]);  // sh_b1 flat [2*DS] == concat index
          outb[(size_t)(m0 + ml) * 2048 + ng] = __float2bfloat16(s);
        } else if constexpr (MODE == 1) {
          outf[(size_t)(m0 + ml) * DIM + ng] = v + bias[ng] + bias[DIM + ng];
        } else if constexpr (MODE == 2) {
          float s = silu_f(v + bias[(size_t)e * DR_K + ng]) * w_s[ml];
          outb[((size_t)seg + m0 + ml) * DR_K + ng] = __float2bfloat16(s);
        } else {
          float wv = w_s[ml];
          outb[((size_t)seg + m0 + ml) * DIM + ng] =
              __float2bfloat16(v + wv * bias[(size_t)e * DIM + ng]);
        }
      }
    }
  }
}

__global__ __launch_bounds__(256) void gemm_sh_l1(
    const __hip_bfloat16* A, const __hip_bfloat16* B, const float* bias,
    __hip_bfloat16* ob, float* of) {
  gemm_body<0>(A, B, bias, ob, of, nullptr, nullptr, nullptr, nullptr);
}
__global__ __launch_bounds__(256) void gemm_sh_l2(
    const __hip_bfloat16* A, const __hip_bfloat16* B, const float* bias,
    __hip_bfloat16* ob, float* of) {
  gemm_body<1>(A, B, bias, ob, of, nullptr, nullptr, nullptr, nullptr);
}
__global__ __launch_bounds__(256) void gemm_re_l1(
    const __hip_bfloat16* A, const __hip_bfloat16* B, const float* bias,
    __hip_bfloat16* ob, const int* tok, const float* wl, const int* seg, const int* pad) {
  gemm_body<2>(A, B, bias, ob, nullptr, tok, wl, seg, pad);
}
__global__ __launch_bounds__(256) void gemm_re_l2(
    const __hip_bfloat16* A, const __hip_bfloat16* B, const float* bias,
    __hip_bfloat16* ob, const int* tok, const float* wl, const int* seg, const int* pad) {
  gemm_body<3>(A, B, bias, ob, nullptr, tok, wl, seg, pad);
}

// ---------------- final combine: out[t] += y_re[pos0] + y_re[pos1] ----------------
__global__ __launch_bounds__(256) void combine_kernel(float* __restrict__ out,
                                                      const __hip_bfloat16* __restrict__ y_re,
                                                      const int* __restrict__ pos_list) {
  int t = blockIdx.x;
  int d0 = threadIdx.x << 3;
  int p0 = pos_list[2 * t], p1 = pos_list[2 * t + 1];
  union { bf16x8 v; __hip_bfloat16 h[8]; } a, b;
  a.v = *(const bf16x8*)(y_re + (size_t)p0 * DIM + d0);
  b.v = *(const bf16x8*)(y_re + (size_t)p1 * DIM + d0);
  float* o = out + (size_t)t * DIM + d0;
  float4 o0 = *(float4*)o, o1 = *(float4*)(o + 4);
  o0.x += __bfloat162float(a.h[0]) + __bfloat162float(b.h[0]);
  o0.y += __bfloat162float(a.h[1]) + __bfloat162float(b.h[1]);
  o0.z += __bfloat162float(a.h[2]) + __bfloat162float(b.h[2]);
  o0.w += __bfloat162float(a.h[3]) + __bfloat162float(b.h[3]);
  o1.x += __bfloat162float(a.h[4]) + __bfloat162float(b.h[4]);
  o1.y += __bfloat162float(a.h[5]) + __bfloat162float(b.h[5]);
  o1.z += __bfloat162float(a.h[6]) + __bfloat162float(b.h[6]);
  o1.w += __bfloat162float(a.h[7]) + __bfloat162float(b.h[7]);
  *(float4*)o = o0;
  *(float4*)(o + 4) = o1;
}

extern "C" void kernel_launch(void* const* d_in, const int* in_sizes, int n_in,
                              void* d_out, int out_size, void* d_ws, size_t ws_size,
                              hipStream_t stream) {
  const float* x     = (const float*)d_in[0];
  const int* step_p  = (const int*)d_in[1];
  const float* rw    = (const float*)d_in[2];
  const float* re_w1 = (const float*)d_in[3];
  const float* re_b1 = (const float*)d_in[4];
  const float* re_w2 = (const float*)d_in[5];
  const float* re_b2 = (const float*)d_in[6];
  const float* sh_w1 = (const float*)d_in[7];
  const float* sh_b1 = (const float*)d_in[8];
  const float* sh_w2 = (const float*)d_in[9];
  const float* sh_b2 = (const float*)d_in[10];
  float* out = (float*)d_out;

  char* w = (char*)d_ws;
  auto take = [&](size_t bytes) {
    char* p = w;
    w += (bytes + 255) & ~(size_t)255;
    return p;
  };
  // NOTE ordering: xb,h_sh,w1t_sh,w2t_sh form a contiguous ~151 MB region that
  // is entirely dead before gemm_re_l2 runs; y_re (142.6 MB) aliases it.
  __hip_bfloat16* xb     = (__hip_bfloat16*)take((size_t)T_TOK * DIM * 2);
  __hip_bfloat16* h_sh   = (__hip_bfloat16*)take((size_t)T_TOK * 2048 * 2);
  __hip_bfloat16* w1t_sh = (__hip_bfloat16*)take((size_t)2 * DS_K * DIM * 2);
  __hip_bfloat16* w2t_sh = (__hip_bfloat16*)take((size_t)DIM * 2048 * 2);
  __hip_bfloat16* h_re   = (__hip_bfloat16*)take((size_t)MAXROWS * DR_K * 2);
  __hip_bfloat16* w1t_re = (__hip_bfloat16*)take((size_t)NEXP * DR_K * DIM * 2);
  __hip_bfloat16* w2t_re = (__hip_bfloat16*)take((size_t)NEXP * DIM * DR_K * 2);
  int* tk_idx   = (int*)take((size_t)T_TOK * 2 * 4);
  float* tk_w   = (float*)take((size_t)T_TOK * 2 * 4);
  int* ctrl     = (int*)take(512);
  int* tok_list = (int*)take((size_t)MAXROWS * 4);
  float* w_list = (float*)take((size_t)MAXROWS * 4);
  int* pos_list = (int*)take((size_t)T_TOK * 2 * 4);
  int* cnt = ctrl, *cnt2 = ctrl + 16, *seg = ctrl + 32, *padded = ctrl + 56;

  __hip_bfloat16* y_re = (__hip_bfloat16*)d_ws;  // aliases xb..w2t_sh (dead by then)

  hipMemsetAsync(ctrl, 0, 512, stream);
  cast_kernel<<<T_TOK * DIM / 8 / 256, 256, 0, stream>>>(x, xb);
  transpose_cast<<<dim3(DS_K / 32, DIM / 32, 2), 256, 0, stream>>>(sh_w1, w1t_sh, DIM, DS_K);
  transpose_cast<<<dim3(DIM / 32, 2048 / 32, 1), 256, 0, stream>>>(sh_w2, w2t_sh, 2048, DIM);
  transpose_cast<<<dim3(DR_K / 32, DIM / 32, NEXP), 256, 0, stream>>>(re_w1, w1t_re, DIM, DR_K);
  transpose_cast<<<dim3(DIM / 32, DR_K / 32, NEXP), 256, 0, stream>>>(re_w2, w2t_re, DR_K, DIM);
  router_kernel<<<T_TOK, 256, 0, stream>>>(x, rw, step_p, tk_idx, tk_w, cnt);
  scan_kernel<<<1, 32, 0, stream>>>(cnt, seg, padded);
  scatter_kernel<<<T_TOK / 256, 256, 0, stream>>>(tk_idx, tk_w, seg, cnt2, tok_list, w_list,
                                                  pos_list);
  pad_kernel<<<NEXP, 128, 0, stream>>>(cnt, padded, seg, tok_list, w_list);

  // shared L1: [T,2048] = xb @ concat(sh_w1), silu -> h_sh
  gemm_sh_l1<<<dim3(16, 128, 1), 256, 0, stream>>>(xb, w1t_sh, sh_b1, h_sh, nullptr);
  // routed L1: gathered rows -> h_re (cw folded in)
  gemm_re_l1<<<dim3(4, 128, NEXP), 256, 0, stream>>>(xb, w1t_re, re_b1, h_re,
                                                     tok_list, w_list, seg, padded);
  // shared L2: writes out (f32 store, covers all of out). Last reader of h_sh/w2t_sh.
  gemm_sh_l2<<<dim3(16, 128, 1), 256, 0, stream>>>(h_sh, w2t_sh, sh_b2, nullptr, out);
  // routed L2: dense bf16 rows into y_re (aliases dead xb..w2t_sh region)
  gemm_re_l2<<<dim3(16, 128, NEXP), 256, 0, stream>>>(h_re, w2t_re, re_b2, y_re,
                                                      tok_list, w_list, seg, padded);
  // final: out[t] += y_re[pos0] + y_re[pos1]
  combine_kernel<<<T_TOK, 256, 0, stream>>>(out, y_re, pos_list);
}

// Round 3
// 1248.754 us; speedup vs baseline: 1.2047x; 1.0258x over previous
//
#include <hip/hip_runtime.h>
#include <hip/hip_bf16.h>
#include <stdint.h>

// ChainOfExperts MoE: shared 2-expert MLP + top-2-of-16 routed experts.
// T=16384 tokens, D=2048, DR=512, DS=1024. bf16 MFMA compute, f32 router.
// R2: routed-L2 atomic scatter -> dense y_re + gather-combine.
// R3: router fused into cast kernel (f32, exact); 64x64 vectorized transposes.

#define DEV static __device__ __forceinline__

typedef __attribute__((ext_vector_type(8))) short bf16x8;
typedef __attribute__((ext_vector_type(4))) float f32x4;

constexpr int T_TOK = 16384;
constexpr int DIM   = 2048;
constexpr int NEXP  = 16;
constexpr int DR_K  = 512;
constexpr int DS_K  = 1024;
constexpr int MAXROWS = 34816;  // T*K + E*127 rounded up

DEV void gload16(const void* g, void* l) {
  __builtin_amdgcn_global_load_lds(
      (const __attribute__((address_space(1))) unsigned int*)g,
      (__attribute__((address_space(3))) unsigned int*)l, 16, 0, 0);
}

DEV float silu_f(float v) { return v / (1.f + __expf(-v)); }

// ---------------- fused cast + router: block b == token row b ----------------
// Reads x row in f32 (float4), writes bf16 row, computes 16 logits in f32,
// softmax + top-2 + per-expert count atomics. Replaces cast_kernel+router_kernel.
__global__ __launch_bounds__(256) void cast_router_kernel(
    const float* __restrict__ x, __hip_bfloat16* __restrict__ xb,
    const float* __restrict__ rw_all, const int* __restrict__ step_p,
    int* __restrict__ tk_idx, float* __restrict__ tk_w, int* __restrict__ cnt) {
  int t = blockIdx.x, tid = threadIdx.x;
  const float* xr = x + (size_t)t * DIM;
  const float4* xp = (const float4*)(xr + tid * 8);
  float4 v0 = xp[0], v1 = xp[1];
  union { bf16x8 v; __hip_bfloat16 h[8]; } r;
  float xv[8] = {v0.x, v0.y, v0.z, v0.w, v1.x, v1.y, v1.z, v1.w};
#pragma unroll
  for (int j = 0; j < 8; ++j) r.h[j] = __float2bfloat16(xv[j]);
  ((bf16x8*)(xb + (size_t)t * DIM))[tid] = r.v;

  // partial logits over this thread's 8 x-elements x all 16 experts
  const float* rw = rw_all + (size_t)step_p[0] * DIM * NEXP + (size_t)tid * 8 * NEXP;
  float p[16];
#pragma unroll
  for (int e = 0; e < 16; ++e) p[e] = 0.f;
#pragma unroll
  for (int j = 0; j < 8; ++j) {
    const float4* rr = (const float4*)(rw + j * NEXP);
    float4 a = rr[0], b = rr[1], c = rr[2], d = rr[3];
    float v = xv[j];
    p[0]  += v * a.x; p[1]  += v * a.y; p[2]  += v * a.z; p[3]  += v * a.w;
    p[4]  += v * b.x; p[5]  += v * b.y; p[6]  += v * b.z; p[7]  += v * b.w;
    p[8]  += v * c.x; p[9]  += v * c.y; p[10] += v * c.z; p[11] += v * c.w;
    p[12] += v * d.x; p[13] += v * d.y; p[14] += v * d.z; p[15] += v * d.w;
  }
  // wave butterfly reduce (all 64 lanes end with wave sum)
#pragma unroll
  for (int m = 1; m < 64; m <<= 1) {
#pragma unroll
    for (int e = 0; e < 16; ++e) p[e] += __shfl_xor(p[e], m);
  }
  __shared__ float part[4][16];
  int lane = tid & 63, wv = tid >> 6;
  if (lane < 16) part[wv][lane] = p[lane];
  __syncthreads();
  if (tid == 0) {
    float lg[16];
#pragma unroll
    for (int e = 0; e < 16; ++e)
      lg[e] = part[0][e] + part[1][e] + part[2][e] + part[3][e];
    float mx = lg[0];
    for (int i = 1; i < 16; ++i) mx = fmaxf(mx, lg[i]);
    float pr[16], sum = 0.f;
    for (int i = 0; i < 16; ++i) { pr[i] = expf(lg[i] - mx); sum += pr[i]; }
    float inv = 1.f / sum;
    int b0 = -1, b1 = -1; float w0 = -1.f, w1 = -1.f;
    for (int i = 0; i < 16; ++i) {
      float v = pr[i] * inv;
      if (v > w0)      { w1 = w0; b1 = b0; w0 = v; b0 = i; }
      else if (v > w1) { w1 = v; b1 = i; }
    }
    tk_idx[2 * t] = b0; tk_idx[2 * t + 1] = b1;
    tk_w[2 * t] = w0;   tk_w[2 * t + 1] = w1;
    atomicAdd(&cnt[b0], 1); atomicAdd(&cnt[b1], 1);
  }
}

// ---------------- transpose + cast: in[R][C] f32 -> out[C][R] bf16, batched z ----------------
// 64x64 tile, float4 reads, bf16x8 (32B/lane) writes.
__global__ __launch_bounds__(256) void transpose_cast(const float* __restrict__ in,
                                                      __hip_bfloat16* __restrict__ out,
                                                      int R, int C) {
  __shared__ float t[64][68];
  size_t bo = (size_t)blockIdx.z * R * C;
  in += bo; out += bo;
  int c0 = blockIdx.x * 64, r0 = blockIdx.y * 64;
  int tid = threadIdx.x;
  int rr = tid >> 2, cc0 = (tid & 3) * 16;  // read: row rr, 16 cols
  const float* ip = in + (size_t)(r0 + rr) * C + c0 + cc0;
#pragma unroll
  for (int j = 0; j < 4; ++j)
    *(float4*)&t[rr][cc0 + 4 * j] = *(const float4*)(ip + 4 * j);
  __syncthreads();
  int wr = tid >> 2, wc0 = (tid & 3) * 16;  // write: out row (c0+wr), 16 r's
  union { bf16x8 v; __hip_bfloat16 h[8]; } o0, o1;
#pragma unroll
  for (int k = 0; k < 8; ++k) o0.h[k] = __float2bfloat16(t[wc0 + k][wr]);
#pragma unroll
  for (int k = 0; k < 8; ++k) o1.h[k] = __float2bfloat16(t[wc0 + 8 + k][wr]);
  __hip_bfloat16* op = out + (size_t)(c0 + wr) * R + r0 + wc0;
  *(bf16x8*)op = o0.v;
  *(bf16x8*)(op + 8) = o1.v;
}

// ---------------- scan: padded counts + exclusive offsets ----------------
__global__ void scan_kernel(const int* __restrict__ cnt, int* __restrict__ seg,
                            int* __restrict__ padded) {
  if (threadIdx.x == 0) {
    int off = 0;
    for (int e = 0; e < NEXP; ++e) {
      seg[e] = off;
      int pc = (cnt[e] + 127) & ~127;
      padded[e] = pc;
      off += pc;
    }
    seg[NEXP] = off;
  }
}

// ---------------- scatter tokens into per-expert lists (+ inverse pos map) ----------------
__global__ void scatter_kernel(const int* __restrict__ tk_idx, const float* __restrict__ tk_w,
                               const int* __restrict__ seg, int* __restrict__ cnt2,
                               int* __restrict__ tok_list, float* __restrict__ w_list,
                               int* __restrict__ pos_list) {
  int t = blockIdx.x * 256 + threadIdx.x;
  if (t >= T_TOK) return;
#pragma unroll
  for (int k = 0; k < 2; ++k) {
    int e = tk_idx[2 * t + k];
    int slot = atomicAdd(&cnt2[e], 1);
    int pos = seg[e] + slot;
    tok_list[pos] = t;
    w_list[pos] = tk_w[2 * t + k];
    pos_list[2 * t + k] = pos;
  }
}

// ---------------- pad lists to multiple of 128 (tok 0, weight 0) ----------------
__global__ void pad_kernel(const int* __restrict__ cnt, const int* __restrict__ padded,
                           const int* __restrict__ seg, int* __restrict__ tok_list,
                           float* __restrict__ w_list) {
  int e = blockIdx.x;
  int c = cnt[e], pc = padded[e], s = seg[e];
  for (int i = c + threadIdx.x; i < pc; i += blockDim.x) {
    tok_list[s + i] = 0;
    w_list[s + i] = 0.f;
  }
}

// ---------------- 128x128 MFMA GEMM body, m97 structure ----------------
// MODE 0: shared L1  (A=xb, Bt=w1t_sh concat-N 2048, silu -> h_sh bf16)
// MODE 1: shared L2  (A=h_sh, Bt=w2t_sh, +sum(sh_b2) -> out f32 store)
// MODE 2: routed L1  (A=xb gathered by token list, Bt=w1t_re[e], silu*cw -> h_re bf16)
// MODE 3: routed L2  (A=h_re, Bt=w2t_re[e], y_re bf16 store, w*bias folded)
template <int MODE>
DEV void gemm_body(const __hip_bfloat16* __restrict__ Abase,
                   const __hip_bfloat16* __restrict__ Bt,
                   const float* __restrict__ bias,
                   __hip_bfloat16* __restrict__ outb,
                   float* __restrict__ outf,
                   const int* __restrict__ tok_list,
                   const float* __restrict__ w_list,
                   const int* __restrict__ seg_off,
                   const int* __restrict__ padded_cnt) {
  constexpr int KD = (MODE == 3) ? DR_K : DIM;  // lda == K for all operands
  int tid = threadIdx.x;
  int lane = tid & 63, wid = tid >> 6;
  int wr = wid >> 1, wc = wid & 1;
  int n0 = blockIdx.x * 128;
  int m0 = blockIdx.y * 128;
  int e = blockIdx.z;

  __shared__ __hip_bfloat16 Alds[128 * 32];
  __shared__ __hip_bfloat16 Blds[128 * 32];
  __shared__ int tk_s[128];
  __shared__ float w_s[128];

  int seg = 0;
  if constexpr (MODE >= 2) {
    seg = seg_off[e];
    if (m0 >= padded_cnt[e]) return;
    if (tid < 128) {
      if constexpr (MODE == 2) tk_s[tid] = tok_list[seg + m0 + tid];
      w_s[tid] = w_list[seg + m0 + tid];
    }
    __syncthreads();
  }

  // staging geometry: row = tid>>2 (0..63), 16B chunk = tid&3
  int srow = tid >> 2;
  int kcol = (tid & 3) << 3;  // element offset within row
  const __hip_bfloat16 *Ag0, *Ag1, *Bg0, *Bg1;
  if constexpr (MODE == 0 || MODE == 1) {
    Ag0 = Abase + (size_t)(m0 + srow) * KD + kcol;
    Ag1 = Abase + (size_t)(m0 + srow + 64) * KD + kcol;
  } else if constexpr (MODE == 2) {
    Ag0 = Abase + (size_t)tk_s[srow] * KD + kcol;
    Ag1 = Abase + (size_t)tk_s[srow + 64] * KD + kcol;
  } else {
    Ag0 = Abase + (size_t)(seg + m0 + srow) * KD + kcol;
    Ag1 = Abase + (size_t)(seg + m0 + srow + 64) * KD + kcol;
  }
  if constexpr (MODE == 0) {
    int s = n0 >> 10, nn = n0 & 1023;
    Bg0 = Bt + ((size_t)s * DS_K + nn + srow) * KD + kcol;
    Bg1 = Bt + ((size_t)s * DS_K + nn + srow + 64) * KD + kcol;
  } else if constexpr (MODE == 1) {
    Bg0 = Bt + (size_t)(n0 + srow) * KD + kcol;
    Bg1 = Bt + (size_t)(n0 + srow + 64) * KD + kcol;
  } else if constexpr (MODE == 2) {
    Bg0 = Bt + ((size_t)e * DR_K + n0 + srow) * KD + kcol;
    Bg1 = Bt + ((size_t)e * DR_K + n0 + srow + 64) * KD + kcol;
  } else {
    Bg0 = Bt + ((size_t)e * DIM + n0 + srow) * KD + kcol;
    Bg1 = Bt + ((size_t)e * DIM + n0 + srow + 64) * KD + kcol;
  }

  char* AldsW0 = (char*)Alds + wid * 1024;
  char* AldsW1 = (char*)Alds + 4096 + wid * 1024;
  char* BldsW0 = (char*)Blds + wid * 1024;
  char* BldsW1 = (char*)Blds + 4096 + wid * 1024;

  f32x4 acc[4][4];
#pragma unroll
  for (int i = 0; i < 4; ++i)
#pragma unroll
    for (int j = 0; j < 4; ++j) acc[i][j] = (f32x4){0.f, 0.f, 0.f, 0.f};

  int arow_rd = wr * 64 + (lane & 15);
  int brow_rd = wc * 64 + (lane & 15);
  int krd = (lane >> 4) << 3;

  for (int k0 = 0; k0 < KD; k0 += 32) {
    gload16(Ag0 + k0, AldsW0);
    gload16(Ag1 + k0, AldsW1);
    gload16(Bg0 + k0, BldsW0);
    gload16(Bg1 + k0, BldsW1);
    __syncthreads();  // drains vmcnt before barrier
    bf16x8 a[4], b[4];
    const short* As = (const short*)Alds;
    const short* Bs = (const short*)Blds;
#pragma unroll
    for (int i = 0; i < 4; ++i) {
      a[i] = *(const bf16x8*)(As + (arow_rd + i * 16) * 32 + krd);
      b[i] = *(const bf16x8*)(Bs + (brow_rd + i * 16) * 32 + krd);
    }
#pragma unroll
    for (int mi = 0; mi < 4; ++mi)
#pragma unroll
      for (int ni = 0; ni < 4; ++ni)
        acc[mi][ni] = __builtin_amdgcn_mfma_f32_16x16x32_bf16(a[mi], b[ni], acc[mi][ni], 0, 0, 0);
    __syncthreads();
  }

  // epilogue: C row (reg dim) = A row, C col (lane&15) = Bt row
  int colc = lane & 15;
  int rowb = (lane >> 4) << 2;
#pragma unroll
  for (int mi = 0; mi < 4; ++mi) {
    int mloc = wr * 64 + mi * 16 + rowb;
#pragma unroll
    for (int ni = 0; ni < 4; ++ni) {
      int ng = n0 + wc * 64 + ni * 16 + colc;
#pragma unroll
      for (int j = 0; j < 4; ++j) {
        float v = acc[mi][ni][j];
        int ml = mloc + j;
        if constexpr (MODE == 0) {
          float s = silu_f(v + bias[ng]);  // sh_b1 flat [2*DS] == concat index
          outb[(size_t)(m0 + ml) * 2048 + ng] = __float2bfloat16(s);
        } else if constexpr (MODE == 1) {
          outf[(size_t)(m0 + ml) * DIM + ng] = v + bias[ng] + bias[DIM + ng];
        } else if constexpr (MODE == 2) {
          float s = silu_f(v + bias[(size_t)e * DR_K + ng]) * w_s[ml];
          outb[((size_t)seg + m0 + ml) * DR_K + ng] = __float2bfloat16(s);
        } else {
          float wv = w_s[ml];
          outb[((size_t)seg + m0 + ml) * DIM + ng] =
              __float2bfloat16(v + wv * bias[(size_t)e * DIM + ng]);
        }
      }
    }
  }
}

__global__ __launch_bounds__(256) void gemm_sh_l1(
    const __hip_bfloat16* A, const __hip_bfloat16* B, const float* bias,
    __hip_bfloat16* ob, float* of) {
  gemm_body<0>(A, B, bias, ob, of, nullptr, nullptr, nullptr, nullptr);
}
__global__ __launch_bounds__(256) void gemm_sh_l2(
    const __hip_bfloat16* A, const __hip_bfloat16* B, const float* bias,
    __hip_bfloat16* ob, float* of) {
  gemm_body<1>(A, B, bias, ob, of, nullptr, nullptr, nullptr, nullptr);
}
__global__ __launch_bounds__(256) void gemm_re_l1(
    const __hip_bfloat16* A, const __hip_bfloat16* B, const float* bias,
    __hip_bfloat16* ob, const int* tok, const float* wl, const int* seg, const int* pad) {
  gemm_body<2>(A, B, bias, ob, nullptr, tok, wl, seg, pad);
}
__global__ __launch_bounds__(256) void gemm_re_l2(
    const __hip_bfloat16* A, const __hip_bfloat16* B, const float* bias,
    __hip_bfloat16* ob, const int* tok, const float* wl, const int* seg, const int* pad) {
  gemm_body<3>(A, B, bias, ob, nullptr, tok, wl, seg, pad);
}

// ---------------- final combine: out[t] += y_re[pos0] + y_re[pos1] ----------------
__global__ __launch_bounds__(256) void combine_kernel(float* __restrict__ out,
                                                      const __hip_bfloat16* __restrict__ y_re,
                                                      const int* __restrict__ pos_list) {
  int t = blockIdx.x;
  int d0 = threadIdx.x << 3;
  int p0 = pos_list[2 * t], p1 = pos_list[2 * t + 1];
  union { bf16x8 v; __hip_bfloat16 h[8]; } a, b;
  a.v = *(const bf16x8*)(y_re + (size_t)p0 * DIM + d0);
  b.v = *(const bf16x8*)(y_re + (size_t)p1 * DIM + d0);
  float* o = out + (size_t)t * DIM + d0;
  float4 o0 = *(float4*)o, o1 = *(float4*)(o + 4);
  o0.x += __bfloat162float(a.h[0]) + __bfloat162float(b.h[0]);
  o0.y += __bfloat162float(a.h[1]) + __bfloat162float(b.h[1]);
  o0.z += __bfloat162float(a.h[2]) + __bfloat162float(b.h[2]);
  o0.w += __bfloat162float(a.h[3]) + __bfloat162float(b.h[3]);
  o1.x += __bfloat162float(a.h[4]) + __bfloat162float(b.h[4]);
  o1.y += __bfloat162float(a.h[5]) + __bfloat162float(b.h[5]);
  o1.z += __bfloat162float(a.h[6]) + __bfloat162float(b.h[6]);
  o1.w += __bfloat162float(a.h[7]) + __bfloat162float(b.h[7]);
  *(float4*)o = o0;
  *(float4*)(o + 4) = o1;
}

extern "C" void kernel_launch(void* const* d_in, const int* in_sizes, int n_in,
                              void* d_out, int out_size, void* d_ws, size_t ws_size,
                              hipStream_t stream) {
  const float* x     = (const float*)d_in[0];
  const int* step_p  = (const int*)d_in[1];
  const float* rw    = (const float*)d_in[2];
  const float* re_w1 = (const float*)d_in[3];
  const float* re_b1 = (const float*)d_in[4];
  const float* re_w2 = (const float*)d_in[5];
  const float* re_b2 = (const float*)d_in[6];
  const float* sh_w1 = (const float*)d_in[7];
  const float* sh_b1 = (const float*)d_in[8];
  const float* sh_w2 = (const float*)d_in[9];
  const float* sh_b2 = (const float*)d_in[10];
  float* out = (float*)d_out;

  char* w = (char*)d_ws;
  auto take = [&](size_t bytes) {
    char* p = w;
    w += (bytes + 255) & ~(size_t)255;
    return p;
  };
  // NOTE ordering: xb,h_sh,w1t_sh,w2t_sh form a contiguous ~151 MB region that
  // is entirely dead before gemm_re_l2 runs; y_re (142.6 MB) aliases it.
  __hip_bfloat16* xb     = (__hip_bfloat16*)take((size_t)T_TOK * DIM * 2);
  __hip_bfloat16* h_sh   = (__hip_bfloat16*)take((size_t)T_TOK * 2048 * 2);
  __hip_bfloat16* w1t_sh = (__hip_bfloat16*)take((size_t)2 * DS_K * DIM * 2);
  __hip_bfloat16* w2t_sh = (__hip_bfloat16*)take((size_t)DIM * 2048 * 2);
  __hip_bfloat16* h_re   = (__hip_bfloat16*)take((size_t)MAXROWS * DR_K * 2);
  __hip_bfloat16* w1t_re = (__hip_bfloat16*)take((size_t)NEXP * DR_K * DIM * 2);
  __hip_bfloat16* w2t_re = (__hip_bfloat16*)take((size_t)NEXP * DIM * DR_K * 2);
  int* tk_idx   = (int*)take((size_t)T_TOK * 2 * 4);
  float* tk_w   = (float*)take((size_t)T_TOK * 2 * 4);
  int* ctrl     = (int*)take(512);
  int* tok_list = (int*)take((size_t)MAXROWS * 4);
  float* w_list = (float*)take((size_t)MAXROWS * 4);
  int* pos_list = (int*)take((size_t)T_TOK * 2 * 4);
  int* cnt = ctrl, *cnt2 = ctrl + 16, *seg = ctrl + 32, *padded = ctrl + 56;

  __hip_bfloat16* y_re = (__hip_bfloat16*)d_ws;  // aliases xb..w2t_sh (dead by then)

  hipMemsetAsync(ctrl, 0, 512, stream);
  // fused cast + router (block b == token b); needs cnt zeroed first
  cast_router_kernel<<<T_TOK, 256, 0, stream>>>(x, xb, rw, step_p, tk_idx, tk_w, cnt);
  transpose_cast<<<dim3(DS_K / 64, DIM / 64, 2), 256, 0, stream>>>(sh_w1, w1t_sh, DIM, DS_K);
  transpose_cast<<<dim3(DIM / 64, 2048 / 64, 1), 256, 0, stream>>>(sh_w2, w2t_sh, 2048, DIM);
  transpose_cast<<<dim3(DR_K / 64, DIM / 64, NEXP), 256, 0, stream>>>(re_w1, w1t_re, DIM, DR_K);
  transpose_cast<<<dim3(DIM / 64, DR_K / 64, NEXP), 256, 0, stream>>>(re_w2, w2t_re, DR_K, DIM);
  scan_kernel<<<1, 32, 0, stream>>>(cnt, seg, padded);
  scatter_kernel<<<T_TOK / 256, 256, 0, stream>>>(tk_idx, tk_w, seg, cnt2, tok_list, w_list,
                                                  pos_list);
  pad_kernel<<<NEXP, 128, 0, stream>>>(cnt, padded, seg, tok_list, w_list);

  // shared L1: [T,2048] = xb @ concat(sh_w1), silu -> h_sh
  gemm_sh_l1<<<dim3(16, 128, 1), 256, 0, stream>>>(xb, w1t_sh, sh_b1, h_sh, nullptr);
  // routed L1: gathered rows -> h_re (cw folded in)
  gemm_re_l1<<<dim3(4, 128, NEXP), 256, 0, stream>>>(xb, w1t_re, re_b1, h_re,
                                                     tok_list, w_list, seg, padded);
  // shared L2: writes out (f32 store, covers all of out). Last reader of h_sh/w2t_sh.
  gemm_sh_l2<<<dim3(16, 128, 1), 256, 0, stream>>>(h_sh, w2t_sh, sh_b2, nullptr, out);
  // routed L2: dense bf16 rows into y_re (aliases dead xb..w2t_sh region)
  gemm_re_l2<<<dim3(16, 128, NEXP), 256, 0, stream>>>(h_re, w2t_re, re_b2, y_re,
                                                      tok_list, w_list, seg, padded);
  // final: out[t] += y_re[pos0] + y_re[pos1]
  combine_kernel<<<T_TOK, 256, 0, stream>>>(out, y_re, pos_list);
}

// Round 4
// 987.752 us; speedup vs baseline: 1.5231x; 1.2642x over previous
//
#include <hip/hip_runtime.h>
#include <hip/hip_bf16.h>
#include <stdint.h>

// ChainOfExperts MoE: shared 2-expert MLP + top-2-of-16 routed experts.
// T=16384 tokens, D=2048, DR=512, DS=1024. bf16 MFMA compute, f32 router.
// R2: routed-L2 atomic scatter -> dense y_re + gather-combine.
// R3: router fused into cast kernel; 64x64 vectorized transposes.
// R4: router restructured: 8 tokens/block, coalesced float4 rw stream (1KB/wave-instr),
//     x staged in LDS, acc[8][4] per thread (col-group = tid&3), butterfly reduce.

#define DEV static __device__ __forceinline__

typedef __attribute__((ext_vector_type(8))) short bf16x8;
typedef __attribute__((ext_vector_type(4))) float f32x4;

constexpr int T_TOK = 16384;
constexpr int DIM   = 2048;
constexpr int NEXP  = 16;
constexpr int DR_K  = 512;
constexpr int DS_K  = 1024;
constexpr int MAXROWS = 34816;  // T*K + E*127 rounded up

DEV void gload16(const void* g, void* l) {
  __builtin_amdgcn_global_load_lds(
      (const __attribute__((address_space(1))) unsigned int*)g,
      (__attribute__((address_space(3))) unsigned int*)l, 16, 0, 0);
}

DEV float silu_f(float v) { return v / (1.f + __expf(-v)); }

// ---------------- fused cast + router: 8 tokens per block ----------------
// Phase 1: stream 8 contiguous x rows (f32 float4, coalesced) -> LDS f32 + xb bf16.
// Phase 2: stream rw slice as flat float4 (c = i*256+tid, 1KB contiguous per
//          wave-instr); each thread accumulates acc[8 tok][4 cols], col-group=tid&3.
// Reduce: butterfly over lane bits 2..5, LDS combine, threads 0..7 do softmax/top2.
__global__ __launch_bounds__(256) void cast_router_kernel(
    const float* __restrict__ x, __hip_bfloat16* __restrict__ xb,
    const float* __restrict__ rw_all, const int* __restrict__ step_p,
    int* __restrict__ tk_idx, float* __restrict__ tk_w, int* __restrict__ cnt) {
  int tid = threadIdx.x;
  int t0 = blockIdx.x * 8;
  __shared__ float xs[8][DIM];        // 64 KB
  __shared__ float red[4][4][8][4];   // wave, col-group, tok, col

  // phase 1: 8 rows = 4096 float4, flat-contiguous
  const float4* xp = (const float4*)(x + (size_t)t0 * DIM);
#pragma unroll
  for (int i = 0; i < 16; ++i) {
    int f = i * 256 + tid;
    int tk = f >> 9, fo = f & 511;
    float4 v = xp[f];
    *(float4*)&xs[tk][fo * 4] = v;
    union { ushort4 u; __hip_bfloat16 h[4]; } o;
    o.h[0] = __float2bfloat16(v.x); o.h[1] = __float2bfloat16(v.y);
    o.h[2] = __float2bfloat16(v.z); o.h[3] = __float2bfloat16(v.w);
    *(ushort4*)(xb + (size_t)t0 * DIM + (size_t)f * 4) = o.u;
  }
  __syncthreads();

  // phase 2: rw slice = 8192 float4; c=i*256+tid -> row d=c>>2, col-group cg=tid&3
  const float4* rw4 = (const float4*)(rw_all + (size_t)step_p[0] * DIM * NEXP);
  float acc[8][4];
#pragma unroll
  for (int tk = 0; tk < 8; ++tk)
#pragma unroll
    for (int j = 0; j < 4; ++j) acc[tk][j] = 0.f;
#pragma unroll 4
  for (int i = 0; i < 32; ++i) {
    int c = i * 256 + tid;
    int d = c >> 2;
    float4 wv = rw4[c];
#pragma unroll
    for (int tk = 0; tk < 8; ++tk) {
      float v = xs[tk][d];
      acc[tk][0] += v * wv.x; acc[tk][1] += v * wv.y;
      acc[tk][2] += v * wv.z; acc[tk][3] += v * wv.w;
    }
  }
  // butterfly over lane bits 2..5: every lane ends with wave-sum for its col-group
#pragma unroll
  for (int m = 4; m < 64; m <<= 1) {
#pragma unroll
    for (int tk = 0; tk < 8; ++tk) {
      acc[tk][0] += __shfl_xor(acc[tk][0], m);
      acc[tk][1] += __shfl_xor(acc[tk][1], m);
      acc[tk][2] += __shfl_xor(acc[tk][2], m);
      acc[tk][3] += __shfl_xor(acc[tk][3], m);
    }
  }
  int lane = tid & 63, wvi = tid >> 6;
  if (lane < 4) {  // lane == col-group
#pragma unroll
    for (int tk = 0; tk < 8; ++tk) {
      float4 r = {acc[tk][0], acc[tk][1], acc[tk][2], acc[tk][3]};
      *(float4*)&red[wvi][lane][tk][0] = r;
    }
  }
  __syncthreads();
  if (tid < 8) {
    int t = t0 + tid;
    float lg[16];
#pragma unroll
    for (int e = 0; e < 16; ++e) {
      int cg = e >> 2, j = e & 3;
      lg[e] = red[0][cg][tid][j] + red[1][cg][tid][j] +
              red[2][cg][tid][j] + red[3][cg][tid][j];
    }
    float mx = lg[0];
    for (int i = 1; i < 16; ++i) mx = fmaxf(mx, lg[i]);
    float pr[16], sum = 0.f;
    for (int i = 0; i < 16; ++i) { pr[i] = expf(lg[i] - mx); sum += pr[i]; }
    float inv = 1.f / sum;
    int b0 = -1, b1 = -1; float w0 = -1.f, w1 = -1.f;
    for (int i = 0; i < 16; ++i) {
      float v = pr[i] * inv;
      if (v > w0)      { w1 = w0; b1 = b0; w0 = v; b0 = i; }
      else if (v > w1) { w1 = v; b1 = i; }
    }
    tk_idx[2 * t] = b0; tk_idx[2 * t + 1] = b1;
    tk_w[2 * t] = w0;   tk_w[2 * t + 1] = w1;
    atomicAdd(&cnt[b0], 1); atomicAdd(&cnt[b1], 1);
  }
}

// ---------------- transpose + cast: in[R][C] f32 -> out[C][R] bf16, batched z ----------------
// 64x64 tile, float4 reads, bf16x8 (32B/lane) writes.
__global__ __launch_bounds__(256) void transpose_cast(const float* __restrict__ in,
                                                      __hip_bfloat16* __restrict__ out,
                                                      int R, int C) {
  __shared__ float t[64][68];
  size_t bo = (size_t)blockIdx.z * R * C;
  in += bo; out += bo;
  int c0 = blockIdx.x * 64, r0 = blockIdx.y * 64;
  int tid = threadIdx.x;
  int rr = tid >> 2, cc0 = (tid & 3) * 16;  // read: row rr, 16 cols
  const float* ip = in + (size_t)(r0 + rr) * C + c0 + cc0;
#pragma unroll
  for (int j = 0; j < 4; ++j)
    *(float4*)&t[rr][cc0 + 4 * j] = *(const float4*)(ip + 4 * j);
  __syncthreads();
  int wr = tid >> 2, wc0 = (tid & 3) * 16;  // write: out row (c0+wr), 16 r's
  union { bf16x8 v; __hip_bfloat16 h[8]; } o0, o1;
#pragma unroll
  for (int k = 0; k < 8; ++k) o0.h[k] = __float2bfloat16(t[wc0 + k][wr]);
#pragma unroll
  for (int k = 0; k < 8; ++k) o1.h[k] = __float2bfloat16(t[wc0 + 8 + k][wr]);
  __hip_bfloat16* op = out + (size_t)(c0 + wr) * R + r0 + wc0;
  *(bf16x8*)op = o0.v;
  *(bf16x8*)(op + 8) = o1.v;
}

// ---------------- scan: padded counts + exclusive offsets ----------------
__global__ void scan_kernel(const int* __restrict__ cnt, int* __restrict__ seg,
                            int* __restrict__ padded) {
  if (threadIdx.x == 0) {
    int off = 0;
    for (int e = 0; e < NEXP; ++e) {
      seg[e] = off;
      int pc = (cnt[e] + 127) & ~127;
      padded[e] = pc;
      off += pc;
    }
    seg[NEXP] = off;
  }
}

// ---------------- scatter tokens into per-expert lists (+ inverse pos map) ----------------
__global__ void scatter_kernel(const int* __restrict__ tk_idx, const float* __restrict__ tk_w,
                               const int* __restrict__ seg, int* __restrict__ cnt2,
                               int* __restrict__ tok_list, float* __restrict__ w_list,
                               int* __restrict__ pos_list) {
  int t = blockIdx.x * 256 + threadIdx.x;
  if (t >= T_TOK) return;
#pragma unroll
  for (int k = 0; k < 2; ++k) {
    int e = tk_idx[2 * t + k];
    int slot = atomicAdd(&cnt2[e], 1);
    int pos = seg[e] + slot;
    tok_list[pos] = t;
    w_list[pos] = tk_w[2 * t + k];
    pos_list[2 * t + k] = pos;
  }
}

// ---------------- pad lists to multiple of 128 (tok 0, weight 0) ----------------
__global__ void pad_kernel(const int* __restrict__ cnt, const int* __restrict__ padded,
                           const int* __restrict__ seg, int* __restrict__ tok_list,
                           float* __restrict__ w_list) {
  int e = blockIdx.x;
  int c = cnt[e], pc = padded[e], s = seg[e];
  for (int i = c + threadIdx.x; i < pc; i += blockDim.x) {
    tok_list[s + i] = 0;
    w_list[s + i] = 0.f;
  }
}

// ---------------- 128x128 MFMA GEMM body, m97 structure ----------------
// MODE 0: shared L1  (A=xb, Bt=w1t_sh concat-N 2048, silu -> h_sh bf16)
// MODE 1: shared L2  (A=h_sh, Bt=w2t_sh, +sum(sh_b2) -> out f32 store)
// MODE 2: routed L1  (A=xb gathered by token list, Bt=w1t_re[e], silu*cw -> h_re bf16)
// MODE 3: routed L2  (A=h_re, Bt=w2t_re[e], y_re bf16 store, w*bias folded)
template <int MODE>
DEV void gemm_body(const __hip_bfloat16* __restrict__ Abase,
                   const __hip_bfloat16* __restrict__ Bt,
                   const float* __restrict__ bias,
                   __hip_bfloat16* __restrict__ outb,
                   float* __restrict__ outf,
                   const int* __restrict__ tok_list,
                   const float* __restrict__ w_list,
                   const int* __restrict__ seg_off,
                   const int* __restrict__ padded_cnt) {
  constexpr int KD = (MODE == 3) ? DR_K : DIM;  // lda == K for all operands
  int tid = threadIdx.x;
  int lane = tid & 63, wid = tid >> 6;
  int wr = wid >> 1, wc = wid & 1;
  int n0 = blockIdx.x * 128;
  int m0 = blockIdx.y * 128;
  int e = blockIdx.z;

  __shared__ __hip_bfloat16 Alds[128 * 32];
  __shared__ __hip_bfloat16 Blds[128 * 32];
  __shared__ int tk_s[128];
  __shared__ float w_s[128];

  int seg = 0;
  if constexpr (MODE >= 2) {
    seg = seg_off[e];
    if (m0 >= padded_cnt[e]) return;
    if (tid < 128) {
      if constexpr (MODE == 2) tk_s[tid] = tok_list[seg + m0 + tid];
      w_s[tid] = w_list[seg + m0 + tid];
    }
    __syncthreads();
  }

  // staging geometry: row = tid>>2 (0..63), 16B chunk = tid&3
  int srow = tid >> 2;
  int kcol = (tid & 3) << 3;  // element offset within row
  const __hip_bfloat16 *Ag0, *Ag1, *Bg0, *Bg1;
  if constexpr (MODE == 0 || MODE == 1) {
    Ag0 = Abase + (size_t)(m0 + srow) * KD + kcol;
    Ag1 = Abase + (size_t)(m0 + srow + 64) * KD + kcol;
  } else if constexpr (MODE == 2) {
    Ag0 = Abase + (size_t)tk_s[srow] * KD + kcol;
    Ag1 = Abase + (size_t)tk_s[srow + 64] * KD + kcol;
  } else {
    Ag0 = Abase + (size_t)(seg + m0 + srow) * KD + kcol;
    Ag1 = Abase + (size_t)(seg + m0 + srow + 64) * KD + kcol;
  }
  if constexpr (MODE == 0) {
    int s = n0 >> 10, nn = n0 & 1023;
    Bg0 = Bt + ((size_t)s * DS_K + nn + srow) * KD + kcol;
    Bg1 = Bt + ((size_t)s * DS_K + nn + srow + 64) * KD + kcol;
  } else if constexpr (MODE == 1) {
    Bg0 = Bt + (size_t)(n0 + srow) * KD + kcol;
    Bg1 = Bt + (size_t)(n0 + srow + 64) * KD + kcol;
  } else if constexpr (MODE == 2) {
    Bg0 = Bt + ((size_t)e * DR_K + n0 + srow) * KD + kcol;
    Bg1 = Bt + ((size_t)e * DR_K + n0 + srow + 64) * KD + kcol;
  } else {
    Bg0 = Bt + ((size_t)e * DIM + n0 + srow) * KD + kcol;
    Bg1 = Bt + ((size_t)e * DIM + n0 + srow + 64) * KD + kcol;
  }

  char* AldsW0 = (char*)Alds + wid * 1024;
  char* AldsW1 = (char*)Alds + 4096 + wid * 1024;
  char* BldsW0 = (char*)Blds + wid * 1024;
  char* BldsW1 = (char*)Blds + 4096 + wid * 1024;

  f32x4 acc[4][4];
#pragma unroll
  for (int i = 0; i < 4; ++i)
#pragma unroll
    for (int j = 0; j < 4; ++j) acc[i][j] = (f32x4){0.f, 0.f, 0.f, 0.f};

  int arow_rd = wr * 64 + (lane & 15);
  int brow_rd = wc * 64 + (lane & 15);
  int krd = (lane >> 4) << 3;

  for (int k0 = 0; k0 < KD; k0 += 32) {
    gload16(Ag0 + k0, AldsW0);
    gload16(Ag1 + k0, AldsW1);
    gload16(Bg0 + k0, BldsW0);
    gload16(Bg1 + k0, BldsW1);
    __syncthreads();  // drains vmcnt before barrier
    bf16x8 a[4], b[4];
    const short* As = (const short*)Alds;
    const short* Bs = (const short*)Blds;
#pragma unroll
    for (int i = 0; i < 4; ++i) {
      a[i] = *(const bf16x8*)(As + (arow_rd + i * 16) * 32 + krd);
      b[i] = *(const bf16x8*)(Bs + (brow_rd + i * 16) * 32 + krd);
    }
#pragma unroll
    for (int mi = 0; mi < 4; ++mi)
#pragma unroll
      for (int ni = 0; ni < 4; ++ni)
        acc[mi][ni] = __builtin_amdgcn_mfma_f32_16x16x32_bf16(a[mi], b[ni], acc[mi][ni], 0, 0, 0);
    __syncthreads();
  }

  // epilogue: C row (reg dim) = A row, C col (lane&15) = Bt row
  int colc = lane & 15;
  int rowb = (lane >> 4) << 2;
#pragma unroll
  for (int mi = 0; mi < 4; ++mi) {
    int mloc = wr * 64 + mi * 16 + rowb;
#pragma unroll
    for (int ni = 0; ni < 4; ++ni) {
      int ng = n0 + wc * 64 + ni * 16 + colc;
#pragma unroll
      for (int j = 0; j < 4; ++j) {
        float v = acc[mi][ni][j];
        int ml = mloc + j;
        if constexpr (MODE == 0) {
          float s = silu_f(v + bias[ng]);  // sh_b1 flat [2*DS] == concat index
          outb[(size_t)(m0 + ml) * 2048 + ng] = __float2bfloat16(s);
        } else if constexpr (MODE == 1) {
          outf[(size_t)(m0 + ml) * DIM + ng] = v + bias[ng] + bias[DIM + ng];
        } else if constexpr (MODE == 2) {
          float s = silu_f(v + bias[(size_t)e * DR_K + ng]) * w_s[ml];
          outb[((size_t)seg + m0 + ml) * DR_K + ng] = __float2bfloat16(s);
        } else {
          float wv = w_s[ml];
          outb[((size_t)seg + m0 + ml) * DIM + ng] =
              __float2bfloat16(v + wv * bias[(size_t)e * DIM + ng]);
        }
      }
    }
  }
}

__global__ __launch_bounds__(256) void gemm_sh_l1(
    const __hip_bfloat16* A, const __hip_bfloat16* B, const float* bias,
    __hip_bfloat16* ob, float* of) {
  gemm_body<0>(A, B, bias, ob, of, nullptr, nullptr, nullptr, nullptr);
}
__global__ __launch_bounds__(256) void gemm_sh_l2(
    const __hip_bfloat16* A, const __hip_bfloat16* B, const float* bias,
    __hip_bfloat16* ob, float* of) {
  gemm_body<1>(A, B, bias, ob, of, nullptr, nullptr, nullptr, nullptr);
}
__global__ __launch_bounds__(256) void gemm_re_l1(
    const __hip_bfloat16* A, const __hip_bfloat16* B, const float* bias,
    __hip_bfloat16* ob, const int* tok, const float* wl, const int* seg, const int* pad) {
  gemm_body<2>(A, B, bias, ob, nullptr, tok, wl, seg, pad);
}
__global__ __launch_bounds__(256) void gemm_re_l2(
    const __hip_bfloat16* A, const __hip_bfloat16* B, const float* bias,
    __hip_bfloat16* ob, const int* tok, const float* wl, const int* seg, const int* pad) {
  gemm_body<3>(A, B, bias, ob, nullptr, tok, wl, seg, pad);
}

// ---------------- final combine: out[t] += y_re[pos0] + y_re[pos1] ----------------
__global__ __launch_bounds__(256) void combine_kernel(float* __restrict__ out,
                                                      const __hip_bfloat16* __restrict__ y_re,
                                                      const int* __restrict__ pos_list) {
  int t = blockIdx.x;
  int d0 = threadIdx.x << 3;
  int p0 = pos_list[2 * t], p1 = pos_list[2 * t + 1];
  union { bf16x8 v; __hip_bfloat16 h[8]; } a, b;
  a.v = *(const bf16x8*)(y_re + (size_t)p0 * DIM + d0);
  b.v = *(const bf16x8*)(y_re + (size_t)p1 * DIM + d0);
  float* o = out + (size_t)t * DIM + d0;
  float4 o0 = *(float4*)o, o1 = *(float4*)(o + 4);
  o0.x += __bfloat162float(a.h[0]) + __bfloat162float(b.h[0]);
  o0.y += __bfloat162float(a.h[1]) + __bfloat162float(b.h[1]);
  o0.z += __bfloat162float(a.h[2]) + __bfloat162float(b.h[2]);
  o0.w += __bfloat162float(a.h[3]) + __bfloat162float(b.h[3]);
  o1.x += __bfloat162float(a.h[4]) + __bfloat162float(b.h[4]);
  o1.y += __bfloat162float(a.h[5]) + __bfloat162float(b.h[5]);
  o1.z += __bfloat162float(a.h[6]) + __bfloat162float(b.h[6]);
  o1.w += __bfloat162float(a.h[7]) + __bfloat162float(b.h[7]);
  *(float4*)o = o0;
  *(float4*)(o + 4) = o1;
}

extern "C" void kernel_launch(void* const* d_in, const int* in_sizes, int n_in,
                              void* d_out, int out_size, void* d_ws, size_t ws_size,
                              hipStream_t stream) {
  const float* x     = (const float*)d_in[0];
  const int* step_p  = (const int*)d_in[1];
  const float* rw    = (const float*)d_in[2];
  const float* re_w1 = (const float*)d_in[3];
  const float* re_b1 = (const float*)d_in[4];
  const float* re_w2 = (const float*)d_in[5];
  const float* re_b2 = (const float*)d_in[6];
  const float* sh_w1 = (const float*)d_in[7];
  const float* sh_b1 = (const float*)d_in[8];
  const float* sh_w2 = (const float*)d_in[9];
  const float* sh_b2 = (const float*)d_in[10];
  float* out = (float*)d_out;

  char* w = (char*)d_ws;
  auto take = [&](size_t bytes) {
    char* p = w;
    w += (bytes + 255) & ~(size_t)255;
    return p;
  };
  // NOTE ordering: xb,h_sh,w1t_sh,w2t_sh form a contiguous ~151 MB region that
  // is entirely dead before gemm_re_l2 runs; y_re (142.6 MB) aliases it.
  __hip_bfloat16* xb     = (__hip_bfloat16*)take((size_t)T_TOK * DIM * 2);
  __hip_bfloat16* h_sh   = (__hip_bfloat16*)take((size_t)T_TOK * 2048 * 2);
  __hip_bfloat16* w1t_sh = (__hip_bfloat16*)take((size_t)2 * DS_K * DIM * 2);
  __hip_bfloat16* w2t_sh = (__hip_bfloat16*)take((size_t)DIM * 2048 * 2);
  __hip_bfloat16* h_re   = (__hip_bfloat16*)take((size_t)MAXROWS * DR_K * 2);
  __hip_bfloat16* w1t_re = (__hip_bfloat16*)take((size_t)NEXP * DR_K * DIM * 2);
  __hip_bfloat16* w2t_re = (__hip_bfloat16*)take((size_t)NEXP * DIM * DR_K * 2);
  int* tk_idx   = (int*)take((size_t)T_TOK * 2 * 4);
  float* tk_w   = (float*)take((size_t)T_TOK * 2 * 4);
  int* ctrl     = (int*)take(512);
  int* tok_list = (int*)take((size_t)MAXROWS * 4);
  float* w_list = (float*)take((size_t)MAXROWS * 4);
  int* pos_list = (int*)take((size_t)T_TOK * 2 * 4);
  int* cnt = ctrl, *cnt2 = ctrl + 16, *seg = ctrl + 32, *padded = ctrl + 56;

  __hip_bfloat16* y_re = (__hip_bfloat16*)d_ws;  // aliases xb..w2t_sh (dead by then)

  hipMemsetAsync(ctrl, 0, 512, stream);
  // fused cast + router, 8 tokens per block
  cast_router_kernel<<<T_TOK / 8, 256, 0, stream>>>(x, xb, rw, step_p, tk_idx, tk_w, cnt);
  transpose_cast<<<dim3(DS_K / 64, DIM / 64, 2), 256, 0, stream>>>(sh_w1, w1t_sh, DIM, DS_K);
  transpose_cast<<<dim3(DIM / 64, 2048 / 64, 1), 256, 0, stream>>>(sh_w2, w2t_sh, 2048, DIM);
  transpose_cast<<<dim3(DR_K / 64, DIM / 64, NEXP), 256, 0, stream>>>(re_w1, w1t_re, DIM, DR_K);
  transpose_cast<<<dim3(DIM / 64, DR_K / 64, NEXP), 256, 0, stream>>>(re_w2, w2t_re, DR_K, DIM);
  scan_kernel<<<1, 32, 0, stream>>>(cnt, seg, padded);
  scatter_kernel<<<T_TOK / 256, 256, 0, stream>>>(tk_idx, tk_w, seg, cnt2, tok_list, w_list,
                                                  pos_list);
  pad_kernel<<<NEXP, 128, 0, stream>>>(cnt, padded, seg, tok_list, w_list);

  // shared L1: [T,2048] = xb @ concat(sh_w1), silu -> h_sh
  gemm_sh_l1<<<dim3(16, 128, 1), 256, 0, stream>>>(xb, w1t_sh, sh_b1, h_sh, nullptr);
  // routed L1: gathered rows -> h_re (cw folded in)
  gemm_re_l1<<<dim3(4, 128, NEXP), 256, 0, stream>>>(xb, w1t_re, re_b1, h_re,
                                                     tok_list, w_list, seg, padded);
  // shared L2: writes out (f32 store, covers all of out). Last reader of h_sh/w2t_sh.
  gemm_sh_l2<<<dim3(16, 128, 1), 256, 0, stream>>>(h_sh, w2t_sh, sh_b2, nullptr, out);
  // routed L2: dense bf16 rows into y_re (aliases dead xb..w2t_sh region)
  gemm_re_l2<<<dim3(16, 128, NEXP), 256, 0, stream>>>(h_re, w2t_re, re_b2, y_re,
                                                      tok_list, w_list, seg, padded);
  // final: out[t] += y_re[pos0] + y_re[pos1]
  combine_kernel<<<T_TOK, 256, 0, stream>>>(out, y_re, pos_list);
}